// Round 19
// baseline (92.429 us; speedup 1.0000x reference)
//
#include <hip/hip_runtime.h>

typedef float f32x4 __attribute__((ext_vector_type(4)));
typedef unsigned int u32x4 __attribute__((ext_vector_type(4)));
typedef unsigned int u32x2 __attribute__((ext_vector_type(2)));
typedef __bf16 bf16x8 __attribute__((ext_vector_type(8)));

// ---------------- LDS layout (bytes) ----------------
#define LDS_WET   0        // [128][32]  bf16 :  8192 (We^T [d][k], linear)
#define LDS_W2T   8192     // [128][128] bf16 : 32768 (W2^T [d][k], XOR-swizzled src)
#define LDS_WC1T  40960    // [128][128] bf16 : 32768 (Wc1^T [d][k], XOR-swizzled src)
#define LDS_ACTW  73728    // 8 x [16][136] bf16 : 34816 (wave-local m1 -> m; tail f32 scratch)
#define LDS_FP    108544   // 768 f32 : 3072 (His 0, wd 128, b2 256, bc1 384, wc2 512, hrow 640)
#define LDS_CIDX  111616   // 384 u16 : 768
#define LDS_WCNT  112384   // 17 int : 68
#define LDS_BYTES 112452   // <= 163840

__device__ __forceinline__ unsigned short f2bf(float f) {  // pack kernel only
  unsigned int u = __builtin_bit_cast(unsigned int, f);
  unsigned int r = u + 0x7FFFu + ((u >> 16) & 1u);
  return (unsigned short)(r >> 16);
}
__device__ __forceinline__ unsigned int pk2(float lo, float hi) {
  unsigned short a = __builtin_bit_cast(unsigned short, (__bf16)lo);
  unsigned short b = __builtin_bit_cast(unsigned short, (__bf16)hi);
  return (unsigned int)a | ((unsigned int)b << 16);
}
__device__ __forceinline__ float bflo(unsigned int u) {
  return __builtin_bit_cast(float, u << 16);
}
__device__ __forceinline__ float bfhi(unsigned int u) {
  return __builtin_bit_cast(float, u & 0xFFFF0000u);
}
__device__ __forceinline__ float silu_f(float xv) {
  float t = __builtin_amdgcn_exp2f(-1.44269504088896f * xv);  // exp(-x)
  return xv * __builtin_amdgcn_rcpf(1.0f + t);
}
__device__ __forceinline__ f32x4 mfma16(u32x4 a, u32x4 b, f32x4 c) {
  return __builtin_amdgcn_mfma_f32_16x16x32_bf16(
      __builtin_bit_cast(bf16x8, a), __builtin_bit_cast(bf16x8, b), c, 0, 0, 0);
}
__device__ __forceinline__ void gload_lds16(const void* g, void* l) {
  __builtin_amdgcn_global_load_lds(
      (const __attribute__((address_space(1))) unsigned int*)g,
      (__attribute__((address_space(3))) unsigned int*)l, 16, 0, 0);
}

// ---- fused precompute + weight pack (blocks >= 768 take the pack role) ----
__global__ void egnn_pre(const float* __restrict__ h,
                         const float* __restrict__ msg_w1,
                         const float* __restrict__ msg_b1,
                         const float* __restrict__ msg_w2,
                         const float* __restrict__ coord_w1,
                         float* __restrict__ his,
                         unsigned short* __restrict__ hjw,
                         unsigned short* __restrict__ weP,
                         unsigned short* __restrict__ w2P,
                         unsigned short* __restrict__ wc1P) {
  __shared__ float hr[128];
  if (blockIdx.x >= 768) {   // ---- pack role: 64 blocks x 256 threads ----
    const int idx = (blockIdx.x - 768)*256 + threadIdx.x;   // 0..16383
    if (idx < 32*128) {              // weP[d*32+k] = W1[256+k][d] (linear)
      int d = idx >> 5, k = idx & 31;
      weP[idx] = f2bf(msg_w1[(size_t)(256 + k)*128 + d]);
    }
    {                                // swizzled source for LDS read addr^swz
      int d = idx >> 7, k = (idx & 127) ^ ((d & 7) << 3);
      w2P[idx]  = f2bf(msg_w2[(size_t)k*128 + d]);
      wc1P[idx] = f2bf(coord_w1[(size_t)k*128 + d]);
    }
    return;
  }
  const int row = blockIdx.x;      // b*384+n
  const int t = threadIdx.x;       // 0..255
  if (t < 128) hr[t] = h[(size_t)row*128 + t];
  __syncthreads();
  const int col = t & 127;
  const int base = (t < 128) ? 0 : 128;
  float s = (t < 128) ? msg_b1[col] : 0.0f;
  #pragma unroll 8
  for (int k = 0; k < 128; ++k) s += hr[k] * msg_w1[(size_t)(base + k)*128 + col];
  if (t < 128) his[(size_t)row*128 + col] = s;
  else         hjw[(size_t)row*128 + col] = f2bf(s);
}

// ---------------- fused main kernel: one block per (b,i) ----------------
__launch_bounds__(512, 1)
__global__ void egnn_main(
    const float* __restrict__ h, const float* __restrict__ x,
    const float* __restrict__ eattr, const float* __restrict__ amask,
    const float* __restrict__ msg_w1, const float* __restrict__ msg_b2,
    const float* __restrict__ node_w1, const float* __restrict__ node_b1,
    const float* __restrict__ node_w2, const float* __restrict__ node_b2,
    const float* __restrict__ coord_b1, const float* __restrict__ coord_w2,
    const float* __restrict__ ln_g, const float* __restrict__ ln_b,
    const int* __restrict__ adj, const float* __restrict__ his,
    const unsigned short* __restrict__ hjw,
    const unsigned short* __restrict__ weP,
    const unsigned short* __restrict__ w2P,
    const unsigned short* __restrict__ wc1P,
    float* __restrict__ out)
{
  extern __shared__ char smem[];
  short* weT  = (short*)(smem + LDS_WET);
  short* w2T  = (short*)(smem + LDS_W2T);
  short* wc1T = (short*)(smem + LDS_WC1T);
  float* fp   = (float*)(smem + LDS_FP);
  float* HisL = fp;          float* wdL  = fp + 128;
  float* b2L  = fp + 256;    float* bc1L = fp + 384;
  float* wc2L = fp + 512;    float* hrow = fp + 640;
  unsigned short* cidx16 = (unsigned short*)(smem + LDS_CIDX);
  int* wcnt = (int*)(smem + LDS_WCNT);
  int* wsc  = wcnt + 8;      // [0..7] offsets, [8] = deg

  const int tid  = threadIdx.x;
  const int bi   = blockIdx.x;            // b*384 + i
  const int bb   = (bi / 384) * 384;
  const int wave = tid >> 6;
  const int lane = tid & 63;
  const int g    = lane >> 4;
  const int lr   = lane & 15;
  const int swz  = (lr & 7) << 3;         // weight-table short-index swizzle
  short* actW = (short*)(smem + LDS_ACTW) + wave*(16*136);  // wave-local [16 j][136]

  // ---- adjacency ballot ----
  const bool pred = (tid < 384) && (adj[(size_t)bi*384 + tid] != 0);
  const unsigned long long bmask = __ballot(pred);
  if (lane == 0) wcnt[wave] = __popcll(bmask);

  // ---- stage pre-packed weights via global_load_lds (linear dest) ----
  {
    const int t16 = tid * 16;
    gload_lds16((const char*)weP + t16, smem + LDS_WET + t16);       // 8192 B
    #pragma unroll
    for (int it = 0; it < 4; ++it) {
      gload_lds16((const char*)w2P  + it*8192 + t16, smem + LDS_W2T  + it*8192 + t16);
      gload_lds16((const char*)wc1P + it*8192 + t16, smem + LDS_WC1T + it*8192 + t16);
    }
  }
  if (tid < 128) {
    HisL[tid] = his[(size_t)bi*128 + tid];
    wdL[tid]  = msg_w1[288*128 + tid];
    b2L[tid]  = msg_b2[tid];
    bc1L[tid] = coord_b1[tid];
    wc2L[tid] = coord_w2[tid];
    hrow[tid] = h[(size_t)bi*128 + tid];
  }
  __syncthreads();   // weights + constants staged (vmcnt drained), wcnt visible

  // ---- hoist loop-invariant weT A-frags to registers ----
  u32x4 awf[8];
  #pragma unroll
  for (int cf = 0; cf < 8; ++cf)
    awf[cf] = *(const u32x4*)(weT + (cf*16 + lr)*32 + g*8);

  if (tid == 0) {
    int run = 0;
    #pragma unroll
    for (int w = 0; w < 8; ++w) { wsc[w] = run; run += wcnt[w]; }
    wsc[8] = run;
  }
  __syncthreads();   // wsc visible
  if (pred) {
    int rank = __popcll(bmask & ((1ull << lane) - 1ull));
    cidx16[wsc[wave] + rank] = (unsigned short)tid;
  }
  const int deg = wsc[8];
  const float xi0 = x[bi*3+0], xi1 = x[bi*3+1], xi2 = x[bi*3+2];
  f32x4 hacc2[8];
  #pragma unroll
  for (int cf = 0; cf < 8; ++cf) hacc2[cf] = (f32x4){0.f, 0.f, 0.f, 0.f};
  float xc0 = 0.0f, xc1 = 0.0f, xc2 = 0.0f;
  __syncthreads();   // cidx visible

  // state A/B for software-pipelined chunk gathers
  float dqA, vmA, c0A, c1A, c2A; u32x4 beA; u32x2 hjA[8];
  float dqB, vmB, c0B, c1B, c2B; u32x4 beB; u32x2 hjB[8];

#define LOAD_STATE(SFX, SIDX) do {                                         \
    const int s_ = (SIDX);                                                 \
    const bool valid_ = (s_ < deg);                                        \
    const int cj_ = valid_ ? (int)cidx16[s_] : 0;                          \
    vm##SFX = valid_ ? 1.0f : 0.0f;                                        \
    const float* xp_ = x + (size_t)(bb + cj_)*3;                           \
    const float r0_ = xi0 - xp_[0], r1_ = xi1 - xp_[1], r2_ = xi2 - xp_[2];\
    dq##SFX = r0_*r0_ + r1_*r1_ + r2_*r2_;                                 \
    const float fc_ = __builtin_amdgcn_rcpf(sqrtf(dq##SFX + 1e-8f) + 1.0f) \
                      * vm##SFX;                                           \
    c0##SFX = fc_*r0_; c1##SFX = fc_*r1_; c2##SFX = fc_*r2_;               \
    const float* ep_ = eattr + ((size_t)bi*384 + cj_)*32 + g*8;            \
    const float4 p0_ = ((const float4*)ep_)[0];                            \
    const float4 p1_ = ((const float4*)ep_)[1];                            \
    be##SFX = (u32x4){pk2(p0_.x, p0_.y), pk2(p0_.z, p0_.w),                \
                      pk2(p1_.x, p1_.y), pk2(p1_.z, p1_.w)};               \
    _Pragma("unroll")                                                      \
    for (int cf_ = 0; cf_ < 8; ++cf_)                                      \
      hj##SFX[cf_] = *(const u32x2*)(hjw + (size_t)(bb + cj_)*128          \
                                     + cf_*16 + 4*g);                      \
  } while (0)

  const int nchunk = (deg + 127) >> 7;
  if (wave*16 < deg) LOAD_STATE(A, wave*16 + lr);

  // ======== barrier-free pipelined chunk loop ========
  for (int ch = 0; ch < nchunk; ++ch) {
    const int sbase = ch*128 + wave*16;
    if (sbase >= deg) continue;          // wave-uniform tail skip
    const int nbase = sbase + 128;
    const bool hasNext = (nbase < deg);  // implies ch+1 < nchunk
    if (hasNext) LOAD_STATE(B, nbase + lr);

    __builtin_amdgcn_s_setprio(1);

    // ---- GEMM1: m1[j=lr][d] for all 128 d; acc-init = His + wd*dsq + Hjs ----
    #pragma unroll
    for (int cf = 0; cf < 8; ++cf) {
      const int dO = cf*16 + 4*g;
      f32x4 hv = *(const f32x4*)(HisL + dO);
      f32x4 wv = *(const f32x4*)(wdL + dO);
      f32x4 acc;
      acc[0] = hv[0] + dqA*wv[0] + bflo(hjA[cf][0]);
      acc[1] = hv[1] + dqA*wv[1] + bfhi(hjA[cf][0]);
      acc[2] = hv[2] + dqA*wv[2] + bflo(hjA[cf][1]);
      acc[3] = hv[3] + dqA*wv[3] + bfhi(hjA[cf][1]);
      acc = mfma16(awf[cf], beA, acc);
      *(u32x2*)(actW + lr*136 + dO) =
          (u32x2){pk2(silu_f(acc[0]), silu_f(acc[1])),
                  pk2(silu_f(acc[2]), silu_f(acc[3]))};
    }

    // ---- GEMM2: m[j=lr][d] = silu(W2^T · m1_row + b2)*vm; overwrites actW ----
    u32x4 bk[4];
    #pragma unroll
    for (int kk = 0; kk < 4; ++kk)
      bk[kk] = *(const u32x4*)(actW + lr*136 + kk*32 + g*8);
    #pragma unroll
    for (int cf = 0; cf < 8; ++cf) {
      const int dO = cf*16 + 4*g;
      f32x4 a = *(const f32x4*)(b2L + dO);
      #pragma unroll
      for (int kk = 0; kk < 4; ++kk) {
        u32x4 aw2 = *(const u32x4*)(w2T + (((cf*16 + lr)*128 + kk*32 + g*8) ^ swz));
        a = mfma16(aw2, bk[kk], a);
      }
      float v0 = silu_f(a[0]) * vmA, v1 = silu_f(a[1]) * vmA;
      float v2 = silu_f(a[2]) * vmA, v3 = silu_f(a[3]) * vmA;
      hacc2[cf][0] += v0; hacc2[cf][1] += v1;
      hacc2[cf][2] += v2; hacc2[cf][3] += v3;
      *(u32x2*)(actW + lr*136 + dO) = (u32x2){pk2(v0, v1), pk2(v2, v3)};
    }

    // ---- GEMM3: c1[d2][j=lr]; cw = sum_d2 silu(c1)*wc2; fold into xc ----
    u32x4 bm[4];
    #pragma unroll
    for (int kk = 0; kk < 4; ++kk)
      bm[kk] = *(const u32x4*)(actW + lr*136 + kk*32 + g*8);
    float cwp = 0.0f;
    #pragma unroll
    for (int cf = 0; cf < 8; ++cf) {
      const int dO = cf*16 + 4*g;
      f32x4 a = *(const f32x4*)(bc1L + dO);
      #pragma unroll
      for (int kk = 0; kk < 4; ++kk) {
        u32x4 aw3 = *(const u32x4*)(wc1T + (((cf*16 + lr)*128 + kk*32 + g*8) ^ swz));
        a = mfma16(aw3, bm[kk], a);
      }
      f32x4 wv = *(const f32x4*)(wc2L + dO);
      cwp += silu_f(a[0])*wv[0] + silu_f(a[1])*wv[1]
           + silu_f(a[2])*wv[2] + silu_f(a[3])*wv[3];
    }
    __builtin_amdgcn_s_setprio(0);
    cwp += __shfl_xor(cwp, 16, 64);
    cwp += __shfl_xor(cwp, 32, 64);
    if (lane < 16) { xc0 += cwp*c0A; xc1 += cwp*c1A; xc2 += cwp*c2A; }

    if (hasNext) {
      dqA = dqB; vmA = vmB; c0A = c0B; c1A = c1B; c2A = c2B; beA = beB;
      #pragma unroll
      for (int cf = 0; cf < 8; ++cf) hjA[cf] = hjB[cf];
    }
  }
#undef LOAD_STATE

  // ======== tail ========
  __syncthreads();   // chunk loop done; safe to reuse actW region
  #pragma unroll
  for (int cf = 0; cf < 8; ++cf) {
    #pragma unroll
    for (int r = 0; r < 4; ++r) {
      float v = hacc2[cf][r];
      v += __shfl_xor(v, 1, 64); v += __shfl_xor(v, 2, 64);
      v += __shfl_xor(v, 4, 64); v += __shfl_xor(v, 8, 64);
      hacc2[cf][r] = v;
    }
  }
  float* actF  = (float*)(smem + LDS_ACTW);  // f32 scratch over dead actW
  float* hpart = actF;            // 8 x 128
  float* xcf   = actF + 1024;     // 384
  float* red   = actF + 1408;     // 512
  float* hagg  = actF + 1920;     // 128
  float* uvec  = actF + 2048;     // 128
  float* lnr   = actF + 2176;     // 4
  if (lr == 0) {
    #pragma unroll
    for (int cf = 0; cf < 8; ++cf)
      #pragma unroll
      for (int r = 0; r < 4; ++r)
        hpart[wave*128 + cf*16 + 4*g + r] = hacc2[cf][r];
  }
  if (lane < 16) {
    const int idx = wave*16 + lr;
    xcf[idx] = xc0; xcf[128 + idx] = xc1; xcf[256 + idx] = xc2;
  }
  __syncthreads();
  if (tid < 128) {
    float s = 0.0f;
    #pragma unroll
    for (int w = 0; w < 8; ++w) s += hpart[w*128 + tid];
    hagg[tid] = s;
  }
  if (tid < 3) {
    float sx = 0.0f;
    #pragma unroll 8
    for (int j = 0; j < 128; ++j) sx += xcf[tid*128 + j];
    out[98304 + (size_t)bi*3 + tid] = x[bi*3 + tid] + sx * amask[bi];
  }
  __syncthreads();

  // ---- node MLP layer 1: u = silu([h, hagg] @ node_w1 + b1) ----
  {
    const int d = tid & 127, q = tid >> 7;
    float s = 0.0f;
    for (int k = q*64; k < q*64 + 64; ++k) {
      const float inv = (k < 128) ? hrow[k] : hagg[k - 128];
      s += inv * node_w1[(size_t)k*128 + d];
    }
    red[q*128 + d] = s;
  }
  __syncthreads();
  if (tid < 128)
    uvec[tid] = silu_f(red[tid] + red[128+tid] + red[256+tid] + red[384+tid] + node_b1[tid]);
  __syncthreads();

  // ---- node MLP layer 2 + residual ----
  {
    const int d = tid & 127, q = tid >> 7;
    float s = 0.0f;
    for (int k = q*32; k < q*32 + 32; ++k) s += uvec[k] * node_w2[(size_t)k*128 + d];
    red[q*128 + d] = s;
  }
  __syncthreads();
  float y = 0.0f;
  if (tid < 128)
    y = hrow[tid] + red[tid] + red[128+tid] + red[256+tid] + red[384+tid] + node_b2[tid];

  // ---- LayerNorm across 128 values (2 waves active) ----
  float ssum = (tid < 128) ? y : 0.0f;
  #pragma unroll
  for (int mm = 1; mm < 64; mm <<= 1) ssum += __shfl_xor(ssum, mm, 64);
  if (tid < 128 && lane == 0) lnr[wave] = ssum;
  __syncthreads();
  const float mu = (lnr[0] + lnr[1]) * (1.0f/128.0f);
  float yc = (tid < 128) ? (y - mu) : 0.0f;
  float sq = yc * yc;
  #pragma unroll
  for (int mm = 1; mm < 64; mm <<= 1) sq += __shfl_xor(sq, mm, 64);
  if (tid < 128 && lane == 0) lnr[2 + wave] = sq;
  __syncthreads();
  if (tid < 128) {
    const float var = (lnr[2] + lnr[3]) * (1.0f/128.0f);
    out[(size_t)bi*128 + tid] = yc * rsqrtf(var + 1e-3f) * ln_g[tid] + ln_b[tid];
  }
}

extern "C" void kernel_launch(void* const* d_in, const int* in_sizes, int n_in,
                              void* d_out, int out_size, void* d_ws, size_t ws_size,
                              hipStream_t stream) {
  const float* h        = (const float*)d_in[0];
  const float* x        = (const float*)d_in[1];
  const float* eattr    = (const float*)d_in[2];
  const float* amask    = (const float*)d_in[3];
  const float* msg_w1   = (const float*)d_in[4];
  const float* msg_b1   = (const float*)d_in[5];
  const float* msg_w2   = (const float*)d_in[6];
  const float* msg_b2   = (const float*)d_in[7];
  const float* node_w1  = (const float*)d_in[8];
  const float* node_b1  = (const float*)d_in[9];
  const float* node_w2  = (const float*)d_in[10];
  const float* node_b2  = (const float*)d_in[11];
  const float* coord_w1 = (const float*)d_in[12];
  const float* coord_b1 = (const float*)d_in[13];
  const float* coord_w2 = (const float*)d_in[14];
  const float* ln_g     = (const float*)d_in[15];
  const float* ln_b     = (const float*)d_in[16];
  const int*   adj      = (const int*)d_in[17];
  float* out = (float*)d_out;
  // workspace layout
  float* his = (float*)d_ws;                                          // 393216 B
  unsigned short* hjw  = (unsigned short*)((char*)d_ws + 393216);     // 196608 B
  unsigned short* weP  = (unsigned short*)((char*)d_ws + 589824);     //   8192 B
  unsigned short* w2P  = (unsigned short*)((char*)d_ws + 598016);     //  32768 B
  unsigned short* wc1P = (unsigned short*)((char*)d_ws + 630784);     //  32768 B -> 663552 total

  hipFuncSetAttribute((const void*)egnn_main,
                      hipFuncAttributeMaxDynamicSharedMemorySize, LDS_BYTES);

  egnn_pre<<<832, 256, 0, stream>>>(h, msg_w1, msg_b1, msg_w2, coord_w1,
                                    his, hjw, weP, w2P, wc1P);
  egnn_main<<<768, 512, LDS_BYTES, stream>>>(h, x, eattr, amask, msg_w1,
      msg_b2, node_w1, node_b1, node_w2, node_b2, coord_b1, coord_w2,
      ln_g, ln_b, adj, his, hjw, weP, w2P, wc1P, out);
}

// Round 20
// 73.317 us; speedup vs baseline: 1.2607x; 1.2607x over previous
//
#include <hip/hip_runtime.h>

typedef float f32x4 __attribute__((ext_vector_type(4)));
typedef unsigned int u32x4 __attribute__((ext_vector_type(4)));
typedef unsigned int u32x2 __attribute__((ext_vector_type(2)));
typedef __bf16 bf16x8 __attribute__((ext_vector_type(8)));

// ---------------- LDS layout (bytes) ----------------
#define LDS_WET   0        // [128][32]  bf16 :  8192 (We^T [d][k], linear)
#define LDS_W2T   8192     // [128][128] bf16 : 32768 (W2^T [d][k], XOR-swizzled src)
#define LDS_WC1T  40960    // [128][128] bf16 : 32768 (Wc1^T [d][k], XOR-swizzled src)
#define LDS_ACTW  73728    // 8 x [16][136] bf16 : 34816 (wave-local m1 -> m; tail f32 scratch)
#define LDS_FP    108544   // 768 f32 : 3072 (His 0, wd 128, b2 256, bc1 384, wc2 512, hrow 640)
#define LDS_CIDX  111616   // 384 u16 : 768
#define LDS_WCNT  112384   // 17 int : 68
#define LDS_BYTES 112452   // <= 163840

__device__ __forceinline__ unsigned short f2bf(float f) {  // pack role only
  unsigned int u = __builtin_bit_cast(unsigned int, f);
  unsigned int r = u + 0x7FFFu + ((u >> 16) & 1u);
  return (unsigned short)(r >> 16);
}
__device__ __forceinline__ unsigned int pk2(float lo, float hi) {
  unsigned short a = __builtin_bit_cast(unsigned short, (__bf16)lo);
  unsigned short b = __builtin_bit_cast(unsigned short, (__bf16)hi);
  return (unsigned int)a | ((unsigned int)b << 16);
}
__device__ __forceinline__ float bflo(unsigned int u) {
  return __builtin_bit_cast(float, u << 16);
}
__device__ __forceinline__ float bfhi(unsigned int u) {
  return __builtin_bit_cast(float, u & 0xFFFF0000u);
}
__device__ __forceinline__ float silu_f(float xv) {
  float t = __builtin_amdgcn_exp2f(-1.44269504088896f * xv);  // exp(-x)
  return xv * __builtin_amdgcn_rcpf(1.0f + t);
}
__device__ __forceinline__ f32x4 mfma16(u32x4 a, u32x4 b, f32x4 c) {
  return __builtin_amdgcn_mfma_f32_16x16x32_bf16(
      __builtin_bit_cast(bf16x8, a), __builtin_bit_cast(bf16x8, b), c, 0, 0, 0);
}
__device__ __forceinline__ void gload_lds16(const void* g, void* l) {
  __builtin_amdgcn_global_load_lds(
      (const __attribute__((address_space(1))) unsigned int*)g,
      (__attribute__((address_space(3))) unsigned int*)l, 16, 0, 0);
}

// ---- fused precompute + weight pack (blocks >= 768 take the pack role) ----
__global__ void egnn_pre(const float* __restrict__ h,
                         const float* __restrict__ msg_w1,
                         const float* __restrict__ msg_b1,
                         const float* __restrict__ msg_w2,
                         const float* __restrict__ coord_w1,
                         float* __restrict__ his,
                         unsigned short* __restrict__ hjw,
                         unsigned short* __restrict__ weP,
                         unsigned short* __restrict__ w2P,
                         unsigned short* __restrict__ wc1P) {
  __shared__ float hr[128];
  if (blockIdx.x >= 768) {   // ---- pack role: 64 blocks x 256 threads ----
    const int idx = (blockIdx.x - 768)*256 + threadIdx.x;   // 0..16383
    if (idx < 32*128) {              // weP[d*32+k] = W1[256+k][d] (linear)
      int d = idx >> 5, k = idx & 31;
      weP[idx] = f2bf(msg_w1[(size_t)(256 + k)*128 + d]);
    }
    {                                // swizzled source for LDS read addr^swz
      int d = idx >> 7, k = (idx & 127) ^ ((d & 7) << 3);
      w2P[idx]  = f2bf(msg_w2[(size_t)k*128 + d]);
      wc1P[idx] = f2bf(coord_w1[(size_t)k*128 + d]);
    }
    return;
  }
  const int row = blockIdx.x;      // b*384+n
  const int t = threadIdx.x;       // 0..255
  if (t < 128) hr[t] = h[(size_t)row*128 + t];
  __syncthreads();
  const int col = t & 127;
  const int base = (t < 128) ? 0 : 128;
  float s = (t < 128) ? msg_b1[col] : 0.0f;
  #pragma unroll 8
  for (int k = 0; k < 128; ++k) s += hr[k] * msg_w1[(size_t)(base + k)*128 + col];
  if (t < 128) his[(size_t)row*128 + col] = s;
  else         hjw[(size_t)row*128 + col] = f2bf(s);
}

// ---------------- fused main kernel: one block per (b,i) ----------------
__launch_bounds__(512, 1)
__global__ void egnn_main(
    const float* __restrict__ h, const float* __restrict__ x,
    const float* __restrict__ eattr, const float* __restrict__ amask,
    const float* __restrict__ msg_w1, const float* __restrict__ msg_b2,
    const float* __restrict__ node_w1, const float* __restrict__ node_b1,
    const float* __restrict__ node_w2, const float* __restrict__ node_b2,
    const float* __restrict__ coord_b1, const float* __restrict__ coord_w2,
    const float* __restrict__ ln_g, const float* __restrict__ ln_b,
    const int* __restrict__ adj, const float* __restrict__ his,
    const unsigned short* __restrict__ hjw,
    const unsigned short* __restrict__ weP,
    const unsigned short* __restrict__ w2P,
    const unsigned short* __restrict__ wc1P,
    float* __restrict__ out)
{
  extern __shared__ char smem[];
  short* weT  = (short*)(smem + LDS_WET);
  short* w2T  = (short*)(smem + LDS_W2T);
  short* wc1T = (short*)(smem + LDS_WC1T);
  float* fp   = (float*)(smem + LDS_FP);
  float* HisL = fp;          float* wdL  = fp + 128;
  float* b2L  = fp + 256;    float* bc1L = fp + 384;
  float* wc2L = fp + 512;    float* hrow = fp + 640;
  unsigned short* cidx16 = (unsigned short*)(smem + LDS_CIDX);
  int* wcnt = (int*)(smem + LDS_WCNT);
  int* wsc  = wcnt + 8;      // [0..7] offsets, [8] = deg

  const int tid  = threadIdx.x;
  const int bi   = blockIdx.x;            // b*384 + i
  const int bb   = (bi / 384) * 384;
  const int wave = tid >> 6;
  const int lane = tid & 63;
  const int g    = lane >> 4;
  const int lr   = lane & 15;
  const int swz  = (lr & 7) << 3;         // weight-table short-index swizzle
  short* actW = (short*)(smem + LDS_ACTW) + wave*(16*136);  // wave-local [16 j][136]

  // ---- adjacency ballot ----
  const bool pred = (tid < 384) && (adj[(size_t)bi*384 + tid] != 0);
  const unsigned long long bmask = __ballot(pred);
  if (lane == 0) wcnt[wave] = __popcll(bmask);

  // ---- stage pre-packed weights via global_load_lds (linear dest) ----
  {
    const int t16 = tid * 16;
    gload_lds16((const char*)weP + t16, smem + LDS_WET + t16);       // 8192 B
    #pragma unroll
    for (int it = 0; it < 4; ++it) {
      gload_lds16((const char*)w2P  + it*8192 + t16, smem + LDS_W2T  + it*8192 + t16);
      gload_lds16((const char*)wc1P + it*8192 + t16, smem + LDS_WC1T + it*8192 + t16);
    }
  }
  if (tid < 128) {
    HisL[tid] = his[(size_t)bi*128 + tid];
    wdL[tid]  = msg_w1[288*128 + tid];
    b2L[tid]  = msg_b2[tid];
    bc1L[tid] = coord_b1[tid];
    wc2L[tid] = coord_w2[tid];
    hrow[tid] = h[(size_t)bi*128 + tid];
  }
  __syncthreads();   // weights + constants staged (vmcnt drained), wcnt visible

  // ---- hoist loop-invariant weT A-frags to registers ----
  u32x4 awf[8];
  #pragma unroll
  for (int cf = 0; cf < 8; ++cf)
    awf[cf] = *(const u32x4*)(weT + (cf*16 + lr)*32 + g*8);

  if (tid == 0) {
    int run = 0;
    #pragma unroll
    for (int w = 0; w < 8; ++w) { wsc[w] = run; run += wcnt[w]; }
    wsc[8] = run;
  }
  __syncthreads();   // wsc visible
  if (pred) {
    int rank = __popcll(bmask & ((1ull << lane) - 1ull));
    cidx16[wsc[wave] + rank] = (unsigned short)tid;
  }
  const int deg = wsc[8];
  const float xi0 = x[bi*3+0], xi1 = x[bi*3+1], xi2 = x[bi*3+2];
  f32x4 hacc2[8];
  #pragma unroll
  for (int cf = 0; cf < 8; ++cf) hacc2[cf] = (f32x4){0.f, 0.f, 0.f, 0.f};
  float xc0 = 0.0f, xc1 = 0.0f, xc2 = 0.0f;
  __syncthreads();   // cidx visible

  // ======== barrier-free chunk loop: wave owns slots ch*128 + wave*16 + lr ========
  const int nchunk = (deg + 127) >> 7;
  for (int ch = 0; ch < nchunk; ++ch) {
    const int sbase = ch*128 + wave*16;
    if (sbase >= deg) continue;          // wave-uniform tail skip
    const int s = sbase + lr;
    const bool valid = (s < deg);
    const int cj = valid ? (int)cidx16[s] : 0;
    const float vm = valid ? 1.0f : 0.0f;
    // geometry (per-lane registers; redundant across g)
    const float* xp = x + (size_t)(bb + cj)*3;
    const float r0 = xi0 - xp[0], r1 = xi1 - xp[1], r2 = xi2 - xp[2];
    const float dq = r0*r0 + r1*r1 + r2*r2;
    const float fc = __builtin_amdgcn_rcpf(sqrtf(dq + 1e-8f) + 1.0f) * vm;
    const float c0 = fc*r0, c1 = fc*r1, c2 = fc*r2;
    // eattr B-frag: this lane's j-row, k = g*8..g*8+7
    const float* ep = eattr + ((size_t)bi*384 + cj)*32 + g*8;
    const float4 p0 = ((const float4*)ep)[0];
    const float4 p1 = ((const float4*)ep)[1];
    const u32x4 be = (u32x4){pk2(p0.x, p0.y), pk2(p0.z, p0.w),
                             pk2(p1.x, p1.y), pk2(p1.z, p1.w)};

    __builtin_amdgcn_s_setprio(1);

    // ---- GEMM1: m1[j=lr][d] for all 128 d; acc-init = His + wd*dsq + Hjs ----
    #pragma unroll
    for (int cf = 0; cf < 8; ++cf) {
      const int dO = cf*16 + 4*g;
      u32x2 hj = *(const u32x2*)(hjw + (size_t)(bb + cj)*128 + dO);
      f32x4 hv = *(const f32x4*)(HisL + dO);
      f32x4 wv = *(const f32x4*)(wdL + dO);
      f32x4 acc;
      acc[0] = hv[0] + dq*wv[0] + bflo(hj[0]);
      acc[1] = hv[1] + dq*wv[1] + bfhi(hj[0]);
      acc[2] = hv[2] + dq*wv[2] + bflo(hj[1]);
      acc[3] = hv[3] + dq*wv[3] + bfhi(hj[1]);
      acc = mfma16(awf[cf], be, acc);
      *(u32x2*)(actW + lr*136 + dO) =
          (u32x2){pk2(silu_f(acc[0]), silu_f(acc[1])),
                  pk2(silu_f(acc[2]), silu_f(acc[3]))};
    }

    // ---- GEMM2: m[j=lr][d] = silu(W2^T · m1_row + b2)*vm; overwrites actW ----
    u32x4 bk[4];
    #pragma unroll
    for (int kk = 0; kk < 4; ++kk)
      bk[kk] = *(const u32x4*)(actW + lr*136 + kk*32 + g*8);
    #pragma unroll
    for (int cf = 0; cf < 8; ++cf) {
      const int dO = cf*16 + 4*g;
      f32x4 a = *(const f32x4*)(b2L + dO);
      #pragma unroll
      for (int kk = 0; kk < 4; ++kk) {
        u32x4 aw2 = *(const u32x4*)(w2T + (((cf*16 + lr)*128 + kk*32 + g*8) ^ swz));
        a = mfma16(aw2, bk[kk], a);
      }
      float v0 = silu_f(a[0]) * vm, v1 = silu_f(a[1]) * vm;
      float v2 = silu_f(a[2]) * vm, v3 = silu_f(a[3]) * vm;
      hacc2[cf][0] += v0; hacc2[cf][1] += v1;
      hacc2[cf][2] += v2; hacc2[cf][3] += v3;
      *(u32x2*)(actW + lr*136 + dO) = (u32x2){pk2(v0, v1), pk2(v2, v3)};
    }

    // ---- GEMM3: c1[d2][j=lr]; cw = sum_d2 silu(c1)*wc2; fold into xc ----
    u32x4 bm[4];
    #pragma unroll
    for (int kk = 0; kk < 4; ++kk)
      bm[kk] = *(const u32x4*)(actW + lr*136 + kk*32 + g*8);
    float cwp = 0.0f;
    #pragma unroll
    for (int cf = 0; cf < 8; ++cf) {
      const int dO = cf*16 + 4*g;
      f32x4 a = *(const f32x4*)(bc1L + dO);
      #pragma unroll
      for (int kk = 0; kk < 4; ++kk) {
        u32x4 aw3 = *(const u32x4*)(wc1T + (((cf*16 + lr)*128 + kk*32 + g*8) ^ swz));
        a = mfma16(aw3, bm[kk], a);
      }
      f32x4 wv = *(const f32x4*)(wc2L + dO);
      cwp += silu_f(a[0])*wv[0] + silu_f(a[1])*wv[1]
           + silu_f(a[2])*wv[2] + silu_f(a[3])*wv[3];
    }
    __builtin_amdgcn_s_setprio(0);
    cwp += __shfl_xor(cwp, 16, 64);
    cwp += __shfl_xor(cwp, 32, 64);
    if (lane < 16) { xc0 += cwp*c0; xc1 += cwp*c1; xc2 += cwp*c2; }
  }

  // ======== tail ========
  __syncthreads();   // chunk loop done; safe to reuse actW region
  #pragma unroll
  for (int cf = 0; cf < 8; ++cf) {
    #pragma unroll
    for (int r = 0; r < 4; ++r) {
      float v = hacc2[cf][r];
      v += __shfl_xor(v, 1, 64); v += __shfl_xor(v, 2, 64);
      v += __shfl_xor(v, 4, 64); v += __shfl_xor(v, 8, 64);
      hacc2[cf][r] = v;
    }
  }
  float* actF  = (float*)(smem + LDS_ACTW);  // f32 scratch over dead actW
  float* hpart = actF;            // 8 x 128
  float* xcf   = actF + 1024;     // 384
  float* red   = actF + 1408;     // 512
  float* hagg  = actF + 1920;     // 128
  float* uvec  = actF + 2048;     // 128
  float* lnr   = actF + 2176;     // 4
  if (lr == 0) {
    #pragma unroll
    for (int cf = 0; cf < 8; ++cf)
      #pragma unroll
      for (int r = 0; r < 4; ++r)
        hpart[wave*128 + cf*16 + 4*g + r] = hacc2[cf][r];
  }
  if (lane < 16) {
    const int idx = wave*16 + lr;
    xcf[idx] = xc0; xcf[128 + idx] = xc1; xcf[256 + idx] = xc2;
  }
  __syncthreads();
  if (tid < 128) {
    float s = 0.0f;
    #pragma unroll
    for (int w = 0; w < 8; ++w) s += hpart[w*128 + tid];
    hagg[tid] = s;
  }
  if (tid < 3) {
    float sx = 0.0f;
    #pragma unroll 8
    for (int j = 0; j < 128; ++j) sx += xcf[tid*128 + j];
    out[98304 + (size_t)bi*3 + tid] = x[bi*3 + tid] + sx * amask[bi];
  }
  __syncthreads();

  // ---- node MLP layer 1: u = silu([h, hagg] @ node_w1 + b1) ----
  {
    const int d = tid & 127, q = tid >> 7;
    float s = 0.0f;
    for (int k = q*64; k < q*64 + 64; ++k) {
      const float inv = (k < 128) ? hrow[k] : hagg[k - 128];
      s += inv * node_w1[(size_t)k*128 + d];
    }
    red[q*128 + d] = s;
  }
  __syncthreads();
  if (tid < 128)
    uvec[tid] = silu_f(red[tid] + red[128+tid] + red[256+tid] + red[384+tid] + node_b1[tid]);
  __syncthreads();

  // ---- node MLP layer 2 + residual ----
  {
    const int d = tid & 127, q = tid >> 7;
    float s = 0.0f;
    for (int k = q*32; k < q*32 + 32; ++k) s += uvec[k] * node_w2[(size_t)k*128 + d];
    red[q*128 + d] = s;
  }
  __syncthreads();
  float y = 0.0f;
  if (tid < 128)
    y = hrow[tid] + red[tid] + red[128+tid] + red[256+tid] + red[384+tid] + node_b2[tid];

  // ---- LayerNorm across 128 values (2 waves active) ----
  float ssum = (tid < 128) ? y : 0.0f;
  #pragma unroll
  for (int mm = 1; mm < 64; mm <<= 1) ssum += __shfl_xor(ssum, mm, 64);
  if (tid < 128 && lane == 0) lnr[wave] = ssum;
  __syncthreads();
  const float mu = (lnr[0] + lnr[1]) * (1.0f/128.0f);
  float yc = (tid < 128) ? (y - mu) : 0.0f;
  float sq = yc * yc;
  #pragma unroll
  for (int mm = 1; mm < 64; mm <<= 1) sq += __shfl_xor(sq, mm, 64);
  if (tid < 128 && lane == 0) lnr[2 + wave] = sq;
  __syncthreads();
  if (tid < 128) {
    const float var = (lnr[2] + lnr[3]) * (1.0f/128.0f);
    out[(size_t)bi*128 + tid] = yc * rsqrtf(var + 1e-3f) * ln_g[tid] + ln_b[tid];
  }
}

extern "C" void kernel_launch(void* const* d_in, const int* in_sizes, int n_in,
                              void* d_out, int out_size, void* d_ws, size_t ws_size,
                              hipStream_t stream) {
  const float* h        = (const float*)d_in[0];
  const float* x        = (const float*)d_in[1];
  const float* eattr    = (const float*)d_in[2];
  const float* amask    = (const float*)d_in[3];
  const float* msg_w1   = (const float*)d_in[4];
  const float* msg_b1   = (const float*)d_in[5];
  const float* msg_w2   = (const float*)d_in[6];
  const float* msg_b2   = (const float*)d_in[7];
  const float* node_w1  = (const float*)d_in[8];
  const float* node_b1  = (const float*)d_in[9];
  const float* node_w2  = (const float*)d_in[10];
  const float* node_b2  = (const float*)d_in[11];
  const float* coord_w1 = (const float*)d_in[12];
  const float* coord_b1 = (const float*)d_in[13];
  const float* coord_w2 = (const float*)d_in[14];
  const float* ln_g     = (const float*)d_in[15];
  const float* ln_b     = (const float*)d_in[16];
  const int*   adj      = (const int*)d_in[17];
  float* out = (float*)d_out;
  // workspace layout
  float* his = (float*)d_ws;                                          // 393216 B
  unsigned short* hjw  = (unsigned short*)((char*)d_ws + 393216);     // 196608 B
  unsigned short* weP  = (unsigned short*)((char*)d_ws + 589824);     //   8192 B
  unsigned short* w2P  = (unsigned short*)((char*)d_ws + 598016);     //  32768 B
  unsigned short* wc1P = (unsigned short*)((char*)d_ws + 630784);     //  32768 B -> 663552 total

  hipFuncSetAttribute((const void*)egnn_main,
                      hipFuncAttributeMaxDynamicSharedMemorySize, LDS_BYTES);

  egnn_pre<<<832, 256, 0, stream>>>(h, msg_w1, msg_b1, msg_w2, coord_w1,
                                    his, hjw, weP, w2P, wc1P);
  egnn_main<<<768, 512, LDS_BYTES, stream>>>(h, x, eattr, amask, msg_w1,
      msg_b2, node_w1, node_b1, node_w2, node_b2, coord_b1, coord_w2,
      ln_g, ln_b, adj, his, hjw, weP, w2P, wc1P, out);
}